// Round 8
// baseline (191.319 us; speedup 1.0000x reference)
//
#include <hip/hip_runtime.h>

#define IN_DIM  128
#define HIDDEN  512
#define NCLASS  10
#define TSTEPS  512
#define BATCH   512
#define BETA    0.9f
#define THRESH  0.15f

typedef __attribute__((ext_vector_type(8))) short bf16x8;
typedef __attribute__((ext_vector_type(4))) float f32x4;

__device__ __forceinline__ unsigned short f2bf_rne(float f) {
    unsigned int u = __float_as_uint(f);
    u += 0x7FFFu + ((u >> 16) & 1u);
    return (unsigned short)(u >> 16);
}
__device__ __forceinline__ float bf2f(unsigned short h) {
    return __uint_as_float(((unsigned int)h) << 16);
}

// 8 f32 (scaled by s) -> hi bf16x8 + residual-lo bf16x8 (fp32-accurate split)
__device__ __forceinline__ void cvt8s(const float4 a, const float4 b, float s,
                                      bf16x8* hi, bf16x8* lo) {
    float v[8] = {a.x * s, a.y * s, a.z * s, a.w * s,
                  b.x * s, b.y * s, b.z * s, b.w * s};
#pragma unroll
    for (int e = 0; e < 8; ++e) {
        unsigned short h = f2bf_rne(v[e]);
        (*hi)[e] = (short)h;
        (*lo)[e] = (short)f2bf_rne(v[e] - bf2f(h));
    }
}

// ---------- Pass 1: repack x into LANE-LINEAR MFMA fragment tiles ----------
// tile(bblk,t) = 8KB: hi[2048 shorts] then lo[2048 shorts].
// Fragment element for wave-lane i, k-chunk kf at short index kf*512 + i*8
// => each wave ds_read_b128 covers 1KB contiguous -> conflict-free.
__global__ __launch_bounds__(256, 4) void conv_x2(
    const float* __restrict__ x, unsigned short* __restrict__ xt)
{
    const int bid  = blockIdx.x;          // bblk*512 + t
    const int bblk = bid >> 9;
    const int t    = bid & 511;
    const int g    = threadIdx.x;         // 0..255
    const int kf   = g >> 6;
    const int i    = g & 63;
    const int l15  = i & 15;
    const int lg   = i >> 4;

    const float* src = x + ((size_t)(bblk * 16 + l15) * TSTEPS + t) * IN_DIM
                         + kf * 32 + lg * 8;
    const float4* p = reinterpret_cast<const float4*>(src);
    bf16x8 h, l;
    cvt8s(p[0], p[1], 2.0f, &h, &l);

    unsigned short* tile = xt + ((size_t)bblk * TSTEPS + t) * 4096;
    *(bf16x8*)(tile + g * 8)        = h;   // g*8 == kf*512 + i*8
    *(bf16x8*)(tile + 2048 + g * 8) = l;
}

// ---------- Pass 2: fused SNN, async LDS ring + 1-t register lookahead ----
// Per iter t: [vmcnt(10) -> barrier] (tile t+1 landed), stage t+7,
// ds_read frags(t+1) -> next regs, MFMA(t) from current regs (loaded last
// iter, latency hidden under this iter's barrier+reads), LIF recurrence.
// Slot written at iter t ((t+7)&7) was last READ at iter t-2 and drained by
// MFMA(t-1) before the iter-t barrier -> race-free by ordering.
__global__ __launch_bounds__(256, 1) void snn_mfma_l(
    const unsigned short* __restrict__ xt,
    const float* __restrict__ W1, const float* __restrict__ b1,
    float* __restrict__ cnt_ws)
{
    __shared__ char ring[8][8192];   // 64 KB

    const int bid  = blockIdx.x;
    const int hblk = bid >> 5;     // bid%8 == bblk%8 -> x-sharers co-XCD
    const int bblk = bid & 31;
    const int b0   = bblk * 16;
    const int tid  = threadIdx.x;
    const int wave = tid >> 6;
    const int lane = tid & 63;
    const int l15  = lane & 15;
    const int lg   = lane >> 4;
    const int hbase = hblk * 64 + wave * 16;

    // B-operand fragments from W1 (fp32->hi/lo once; held all T steps)
    bf16x8 whi[4], wlo[4];
    {
        const float* wp = W1 + (size_t)(hbase + l15) * IN_DIM + lg * 8;
#pragma unroll
        for (int kf = 0; kf < 4; ++kf) {
            const float4* p = reinterpret_cast<const float4*>(wp + kf * 32);
            cvt8s(p[0], p[1], 1.0f, &whi[kf], &wlo[kf]);
        }
    }
    const float b1h = b1[hbase + l15];

    const char* gb = (const char*)xt + (size_t)bblk * TSTEPS * 8192;
    char* lbase = &ring[0][0];
    const int woff   = wave * 1024;          // wave-uniform LDS offset
    const int lane16 = lane * 16;

    f32x4 mem = {0.f, 0.f, 0.f, 0.f};
    f32x4 cnt = {0.f, 0.f, 0.f, 0.f};

#define STAGE(TT, SLOT)                                                        \
    {                                                                          \
        const char* g_ = gb + (size_t)(TT) * 8192 + woff + lane16;             \
        char* l_ = lbase + (SLOT) * 8192 + woff;                               \
        __builtin_amdgcn_global_load_lds(                                      \
            (const __attribute__((address_space(1))) void*)g_,                 \
            (__attribute__((address_space(3))) void*)l_, 16, 0, 0);            \
        __builtin_amdgcn_global_load_lds(                                      \
            (const __attribute__((address_space(1))) void*)(g_ + 4096),        \
            (__attribute__((address_space(3))) void*)(l_ + 4096), 16, 0, 0);   \
    }

    // double-buffered A fragments (static names only -- no runtime indexing)
    bf16x8 a0h[4], a0l[4], a1h[4], a1l[4];

    // prologue: drain W1 loads; stage tiles 0..6; read tile-0 frags -> a0
    asm volatile("s_waitcnt vmcnt(0)" ::: "memory");
#pragma unroll
    for (int j = 0; j < 7; ++j)
        STAGE(j, j)
    asm volatile("s_waitcnt vmcnt(12)" ::: "memory");   // tile 0 landed
    __builtin_amdgcn_s_barrier();
    asm volatile("" ::: "memory");
    {
        const short* tp = (const short*)&ring[0][0];
#pragma unroll
        for (int kf = 0; kf < 4; ++kf) {
            a0h[kf] = *(const bf16x8*)(tp + kf * 512 + lane * 8);
            a0l[kf] = *(const bf16x8*)(tp + 2048 + kf * 512 + lane * 8);
        }
    }

#define ITER(T_, FCh, FCl, FNh, FNl)                                           \
    {                                                                          \
        /* gate: tile T_+1 landed (<=10 outstanding = tiles T_+2..T_+6) */     \
        asm volatile("s_waitcnt vmcnt(10)" ::: "memory");                      \
        __builtin_amdgcn_s_barrier();                                          \
        asm volatile("" ::: "memory");                                         \
        /* stage tile T_+7 (slot last read at iter T_-2 -> drained) */         \
        {                                                                      \
            int tt = (T_) + 7; if (tt > TSTEPS - 1) tt = TSTEPS - 1;           \
            STAGE(tt, tt & 7)                                                  \
        }                                                                      \
        /* prefetch tile T_+1 fragments into FN (consumed next iter) */        \
        {                                                                      \
            const short* tp = (const short*)&ring[((T_) + 1) & 7][0];          \
            _Pragma("unroll")                                                  \
            for (int kf = 0; kf < 4; ++kf) {                                   \
                FNh[kf] = *(const bf16x8*)(tp + kf * 512 + lane * 8);          \
                FNl[kf] = *(const bf16x8*)(tp + 2048 + kf * 512 + lane * 8);   \
            }                                                                  \
        }                                                                      \
        /* MFMA tile T_ from FC regs (loaded last iter -> latency hidden) */   \
        f32x4 chh = {b1h, b1h, b1h, b1h};                                      \
        f32x4 chl = {0.f, 0.f, 0.f, 0.f};                                      \
        f32x4 clh = {0.f, 0.f, 0.f, 0.f};                                      \
        _Pragma("unroll")                                                      \
        for (int kf = 0; kf < 4; ++kf) {                                       \
            chh = __builtin_amdgcn_mfma_f32_16x16x32_bf16(FCh[kf], whi[kf], chh, 0, 0, 0); \
            chl = __builtin_amdgcn_mfma_f32_16x16x32_bf16(FCh[kf], wlo[kf], chl, 0, 0, 0); \
            clh = __builtin_amdgcn_mfma_f32_16x16x32_bf16(FCl[kf], whi[kf], clh, 0, 0, 0); \
        }                                                                      \
        /* LIF recurrence (snntorch order) */                                  \
        _Pragma("unroll")                                                      \
        for (int r = 0; r < 4; ++r) {                                          \
            float cur = (chh[r] + chl[r]) + clh[r];                            \
            float dec = fmaf(BETA, mem[r], cur);                               \
            mem[r] = (mem[r] > THRESH) ? (dec - THRESH) : dec;                 \
            cnt[r] += (mem[r] > THRESH) ? 1.0f : 0.0f;                         \
        }                                                                      \
    }

    for (int w = 0; w < TSTEPS / 2; ++w) {
        ITER(2 * w,     a0h, a0l, a1h, a1l)
        ITER(2 * w + 1, a1h, a1l, a0h, a0l)
    }
#undef ITER
#undef STAGE

    // store spike counts; C-layout row = lg*4+r, col = l15
    float* cp = cnt_ws + (size_t)b0 * HIDDEN + hbase + l15;
#pragma unroll
    for (int r = 0; r < 4; ++r)
        cp[(size_t)(lg * 4 + r) * HIDDEN] = cnt[r];
}

// ---------- Fallback (proven R2 path) if ws too small ----------
__global__ __launch_bounds__(256, 1) void snn_mfma_lds(
    const float* __restrict__ x, const float* __restrict__ W1,
    const float* __restrict__ b1, float* __restrict__ cnt_ws)
{
    __shared__ short ldsA[2][2][16 * IN_DIM];
    const int bid  = blockIdx.x;
    const int hblk = bid >> 5;
    const int bblk = bid & 31;
    const int b0   = bblk * 16;
    const int tid  = threadIdx.x;
    const int wave = tid >> 6;
    const int lane = tid & 63;
    const int l15  = lane & 15;
    const int lg   = lane >> 4;
    const int hbase = hblk * 64 + wave * 16;

    bf16x8 whi[4], wlo[4];
    {
        const float* wp = W1 + (size_t)(hbase + l15) * IN_DIM + lg * 8;
#pragma unroll
        for (int kf = 0; kf < 4; ++kf) {
            const float4* p = reinterpret_cast<const float4*>(wp + kf * 32);
            cvt8s(p[0], p[1], 1.0f, &whi[kf], &wlo[kf]);
        }
    }
    const float b1h = b1[hbase + l15];
    const int m_w  = wave * 4 + lg;
    const int widx = m_w * IN_DIM + ((l15 ^ (m_w & 7)) * 8);
    const float* xrow = x + ((size_t)(b0 + m_w) * TSTEPS) * IN_DIM + l15 * 8;
    int ridx[4];
#pragma unroll
    for (int kf = 0; kf < 4; ++kf)
        ridx[kf] = l15 * IN_DIM + (((lg + 4 * kf) ^ (l15 & 7)) * 8);

    f32x4 mem = {0.f, 0.f, 0.f, 0.f};
    f32x4 cnt = {0.f, 0.f, 0.f, 0.f};
    {
        const float4* p = reinterpret_cast<const float4*>(xrow);
        bf16x8 h8, l8;
        cvt8s(p[0], p[1], 2.0f, &h8, &l8);
        *(bf16x8*)&ldsA[0][0][widx] = h8;
        *(bf16x8*)&ldsA[0][1][widx] = l8;
    }
    float4 rA0, rA1, rB0, rB1;
    {
        const float4* p1 = reinterpret_cast<const float4*>(xrow + 1 * IN_DIM);
        rA0 = p1[0]; rA1 = p1[1];
        const float4* p2 = reinterpret_cast<const float4*>(xrow + 2 * IN_DIM);
        rB0 = p2[0]; rB1 = p2[1];
    }
    __syncthreads();

#define SNN_BODY(T_CUR, RC0, RC1)                                              \
    {                                                                          \
        const int buf = (T_CUR) & 1;                                           \
        if ((T_CUR) + 1 < TSTEPS) {                                            \
            bf16x8 h8, l8;                                                     \
            cvt8s(RC0, RC1, 2.0f, &h8, &l8);                                   \
            *(bf16x8*)&ldsA[buf ^ 1][0][widx] = h8;                            \
            *(bf16x8*)&ldsA[buf ^ 1][1][widx] = l8;                            \
        }                                                                      \
        bf16x8 ahi[4], alo[4];                                                 \
        _Pragma("unroll")                                                      \
        for (int kf = 0; kf < 4; ++kf) {                                       \
            ahi[kf] = *(const bf16x8*)&ldsA[buf][0][ridx[kf]];                 \
            alo[kf] = *(const bf16x8*)&ldsA[buf][1][ridx[kf]];                 \
        }                                                                      \
        {                                                                      \
            int tld = (T_CUR) + 3;                                             \
            if (tld > TSTEPS - 1) tld = TSTEPS - 1;                            \
            const float4* p = reinterpret_cast<const float4*>(                 \
                xrow + (size_t)tld * IN_DIM);                                  \
            RC0 = p[0]; RC1 = p[1];                                            \
        }                                                                      \
        f32x4 chh = {b1h, b1h, b1h, b1h};                                      \
        f32x4 chl = {0.f, 0.f, 0.f, 0.f};                                      \
        f32x4 clh = {0.f, 0.f, 0.f, 0.f};                                      \
        _Pragma("unroll")                                                      \
        for (int kf = 0; kf < 4; ++kf) {                                       \
            chh = __builtin_amdgcn_mfma_f32_16x16x32_bf16(ahi[kf], whi[kf], chh, 0, 0, 0); \
            chl = __builtin_amdgcn_mfma_f32_16x16x32_bf16(ahi[kf], wlo[kf], chl, 0, 0, 0); \
            clh = __builtin_amdgcn_mfma_f32_16x16x32_bf16(alo[kf], whi[kf], clh, 0, 0, 0); \
        }                                                                      \
        _Pragma("unroll")                                                      \
        for (int r = 0; r < 4; ++r) {                                          \
            float cur = (chh[r] + chl[r]) + clh[r];                            \
            float dec = fmaf(BETA, mem[r], cur);                               \
            mem[r] = (mem[r] > THRESH) ? (dec - THRESH) : dec;                 \
            cnt[r] += (mem[r] > THRESH) ? 1.0f : 0.0f;                         \
        }                                                                      \
        __syncthreads();                                                       \
    }

    for (int t = 0; t < TSTEPS; t += 2) {
        SNN_BODY(t,     rA0, rA1)
        SNN_BODY(t + 1, rB0, rB1)
    }
#undef SNN_BODY

    float* cp = cnt_ws + (size_t)b0 * HIDDEN + hbase + l15;
#pragma unroll
    for (int r = 0; r < 4; ++r)
        cp[(size_t)(lg * 4 + r) * HIDDEN] = cnt[r];
}

// out[b,c] = (sum_h cnt[b,h] * W2[c,h]) / T + b2[c]
__global__ __launch_bounds__(64, 1) void snn_out(
    const float* __restrict__ cnt_ws, const float* __restrict__ W2,
    const float* __restrict__ b2, float* __restrict__ out)
{
    const int b = blockIdx.x;
    const int lane = threadIdx.x;
    float c8[8];
#pragma unroll
    for (int j = 0; j < 8; ++j)
        c8[j] = cnt_ws[(size_t)b * HIDDEN + lane + 64 * j];
#pragma unroll
    for (int c = 0; c < NCLASS; ++c) {
        float s = 0.f;
#pragma unroll
        for (int j = 0; j < 8; ++j)
            s = fmaf(c8[j], W2[c * HIDDEN + lane + 64 * j], s);
#pragma unroll
        for (int off = 32; off >= 1; off >>= 1)
            s += __shfl_xor(s, off, 64);
        if (lane == c)
            out[(size_t)b * NCLASS + c] = s * (1.0f / (float)TSTEPS) + b2[c];
    }
}

extern "C" void kernel_launch(void* const* d_in, const int* in_sizes, int n_in,
                              void* d_out, int out_size, void* d_ws, size_t ws_size,
                              hipStream_t stream) {
    const float* x  = (const float*)d_in[0];
    const float* W1 = (const float*)d_in[1];
    const float* b1 = (const float*)d_in[2];
    const float* W2 = (const float*)d_in[3];
    const float* b2 = (const float*)d_in[4];
    float* out = (float*)d_out;

    const size_t NX = (size_t)BATCH * TSTEPS * IN_DIM;      // 33.55M elems
    float* cnt_ws = (float*)d_ws;                           // [B, H], 1 MB
    unsigned short* xt = (unsigned short*)((char*)d_ws + (1u << 20));
    const size_t need = (1u << 20) + 2 * NX * sizeof(unsigned short);

    if (ws_size >= need) {
        conv_x2<<<dim3(32 * TSTEPS), dim3(256), 0, stream>>>(x, xt);
        snn_mfma_l<<<dim3(256), dim3(256), 0, stream>>>(xt, W1, b1, cnt_ws);
    } else {
        snn_mfma_lds<<<dim3(256), dim3(256), 0, stream>>>(x, W1, b1, cnt_ws);
    }
    snn_out<<<dim3(BATCH), dim3(64), 0, stream>>>(cnt_ws, W2, b2, out);
}

// Round 9
// 171.359 us; speedup vs baseline: 1.1165x; 1.1165x over previous
//
#include <hip/hip_runtime.h>

#define IN_DIM  128
#define HIDDEN  512
#define NCLASS  10
#define TSTEPS  512
#define BATCH   512
#define BETA    0.9f
#define THRESH  0.15f

typedef __attribute__((ext_vector_type(8))) short bf16x8;
typedef __attribute__((ext_vector_type(4))) float f32x4;

__device__ __forceinline__ unsigned short f2bf_rne(float f) {
    unsigned int u = __float_as_uint(f);
    u += 0x7FFFu + ((u >> 16) & 1u);
    return (unsigned short)(u >> 16);
}
__device__ __forceinline__ float bf2f(unsigned short h) {
    return __uint_as_float(((unsigned int)h) << 16);
}

// 8 f32 (scaled by s) -> hi bf16x8 + residual-lo bf16x8 (fp32-accurate split)
__device__ __forceinline__ void cvt8s(const float4 a, const float4 b, float s,
                                      bf16x8* hi, bf16x8* lo) {
    float v[8] = {a.x * s, a.y * s, a.z * s, a.w * s,
                  b.x * s, b.y * s, b.z * s, b.w * s};
#pragma unroll
    for (int e = 0; e < 8; ++e) {
        unsigned short h = f2bf_rne(v[e]);
        (*hi)[e] = (short)h;
        (*lo)[e] = (short)f2bf_rne(v[e] - bf2f(h));
    }
}

// ---------- Pass 1: repack x into LANE-LINEAR MFMA fragment tiles ----------
// tile(bblk,t) = 8KB: hi[2048 shorts] then lo[2048 shorts].
// Fragment element for wave-lane i, k-chunk kf at short index kf*512 + i*8
// => each wave ds_read_b128 covers 1KB contiguous -> conflict-free.
__global__ __launch_bounds__(256, 4) void conv_x2(
    const float* __restrict__ x, unsigned short* __restrict__ xt)
{
    const int bid  = blockIdx.x;          // bblk*512 + t
    const int bblk = bid >> 9;
    const int t    = bid & 511;
    const int g    = threadIdx.x;         // 0..255
    const int kf   = g >> 6;
    const int i    = g & 63;
    const int l15  = i & 15;
    const int lg   = i >> 4;

    const float* src = x + ((size_t)(bblk * 16 + l15) * TSTEPS + t) * IN_DIM
                         + kf * 32 + lg * 8;
    const float4* p = reinterpret_cast<const float4*>(src);
    bf16x8 h, l;
    cvt8s(p[0], p[1], 2.0f, &h, &l);

    unsigned short* tile = xt + ((size_t)bblk * TSTEPS + t) * 4096;
    *(bf16x8*)(tile + g * 8)        = h;   // g*8 == kf*512 + i*8
    *(bf16x8*)(tile + 2048 + g * 8) = l;
}

// ---------- Pass 2: fused SNN, async ring + 2-t phases + SGB-pinned ----
// Per phase (T even): [vmcnt(6) -> barrier] (tiles <=T+2 landed; per-wave
// outstanding = its loads for tiles T+3..T+5), stage tiles T+6,T+7,
// ds_read(T+1)->FB, MFMA(T) from FA, rec(T), ds_read(T+2)->FA, MFMA(T+1)
// from FB, rec(T+1). sched_group_barrier pins this order so every read
// issues one MFMA-cluster (~230cyc) ahead of its consumer.
__global__ __launch_bounds__(256, 1) void snn_mfma_l(
    const unsigned short* __restrict__ xt,
    const float* __restrict__ W1, const float* __restrict__ b1,
    float* __restrict__ cnt_ws)
{
    __shared__ char ring[8][8192];   // 64 KB

    const int bid  = blockIdx.x;
    const int hblk = bid >> 5;     // bid%8 == bblk%8 -> x-sharers co-XCD
    const int bblk = bid & 31;
    const int b0   = bblk * 16;
    const int tid  = threadIdx.x;
    const int wave = tid >> 6;
    const int lane = tid & 63;
    const int l15  = lane & 15;
    const int lg   = lane >> 4;
    const int hbase = hblk * 64 + wave * 16;

    // B-operand fragments from W1 (fp32->hi/lo once; held all T steps)
    bf16x8 whi[4], wlo[4];
    {
        const float* wp = W1 + (size_t)(hbase + l15) * IN_DIM + lg * 8;
#pragma unroll
        for (int kf = 0; kf < 4; ++kf) {
            const float4* p = reinterpret_cast<const float4*>(wp + kf * 32);
            cvt8s(p[0], p[1], 1.0f, &whi[kf], &wlo[kf]);
        }
    }
    const float b1h = b1[hbase + l15];

    const char* gb = (const char*)xt + (size_t)bblk * TSTEPS * 8192;
    char* lbase = &ring[0][0];
    const int woff   = wave * 1024;          // wave-uniform LDS offset
    const int lane16 = lane * 16;

    f32x4 mem = {0.f, 0.f, 0.f, 0.f};
    f32x4 cnt = {0.f, 0.f, 0.f, 0.f};

#define STAGE(TT, SLOT)                                                        \
    {                                                                          \
        const char* g_ = gb + (size_t)(TT) * 8192 + woff + lane16;             \
        char* l_ = lbase + (SLOT) * 8192 + woff;                               \
        __builtin_amdgcn_global_load_lds(                                      \
            (const __attribute__((address_space(1))) void*)g_,                 \
            (__attribute__((address_space(3))) void*)l_, 16, 0, 0);            \
        __builtin_amdgcn_global_load_lds(                                      \
            (const __attribute__((address_space(1))) void*)(g_ + 4096),        \
            (__attribute__((address_space(3))) void*)(l_ + 4096), 16, 0, 0);   \
    }

#define RD8(SLOT, FH, FL)                                                      \
    {                                                                          \
        const short* tp = (const short*)&ring[(SLOT)][0];                      \
        _Pragma("unroll")                                                      \
        for (int kf = 0; kf < 4; ++kf) {                                       \
            FH[kf] = *(const bf16x8*)(tp + kf * 512 + lane * 8);               \
            FL[kf] = *(const bf16x8*)(tp + 2048 + kf * 512 + lane * 8);        \
        }                                                                      \
    }

#define MFMA_REC(FH, FL)                                                       \
    {                                                                          \
        f32x4 chh = {b1h, b1h, b1h, b1h};                                      \
        f32x4 chl = {0.f, 0.f, 0.f, 0.f};                                      \
        f32x4 clh = {0.f, 0.f, 0.f, 0.f};                                      \
        _Pragma("unroll")                                                      \
        for (int kf = 0; kf < 4; ++kf) {                                       \
            chh = __builtin_amdgcn_mfma_f32_16x16x32_bf16(FH[kf], whi[kf], chh, 0, 0, 0); \
            chl = __builtin_amdgcn_mfma_f32_16x16x32_bf16(FH[kf], wlo[kf], chl, 0, 0, 0); \
            clh = __builtin_amdgcn_mfma_f32_16x16x32_bf16(FL[kf], whi[kf], clh, 0, 0, 0); \
        }                                                                      \
        _Pragma("unroll")                                                      \
        for (int r = 0; r < 4; ++r) {                                          \
            float cur = (chh[r] + chl[r]) + clh[r];                            \
            float dec = fmaf(BETA, mem[r], cur);                               \
            mem[r] = (mem[r] > THRESH) ? (dec - THRESH) : dec;                 \
            cnt[r] += (mem[r] > THRESH) ? 1.0f : 0.0f;                         \
        }                                                                      \
    }

#define SGB(M, N) __builtin_amdgcn_sched_group_barrier((M), (N), 0)

// phase: T_ even. FA holds frags(T_) on entry; on exit FA holds frags(T_+2).
#define PHASE(T_)                                                              \
    {                                                                          \
        asm volatile("s_waitcnt vmcnt(6)" ::: "memory");                       \
        __builtin_amdgcn_s_barrier();                                          \
        asm volatile("" ::: "memory");                                         \
        { int t6 = (T_) + 6; const int s6 = t6 & 7;                            \
          if (t6 > TSTEPS - 1) t6 = TSTEPS - 1; STAGE(t6, s6) }                \
        { int t7 = (T_) + 7; const int s7 = t7 & 7;                            \
          if (t7 > TSTEPS - 1) t7 = TSTEPS - 1; STAGE(t7, s7) }                \
        RD8(((T_) + 1) & 7, fBh, fBl)                                          \
        MFMA_REC(fAh, fAl)                                                     \
        RD8(((T_) + 2) & 7, fAh, fAl)                                          \
        MFMA_REC(fBh, fBl)                                                     \
        SGB(0x10, 4);   /* 4 global_load_lds */                                \
        SGB(0x100, 8);  /* ds_read -> FB      */                               \
        SGB(0x8, 12);   /* MFMA(T)            */                               \
        SGB(0x2, 24);   /* recurrence(T)      */                               \
        SGB(0x100, 8);  /* ds_read -> FA      */                               \
        SGB(0x8, 12);   /* MFMA(T+1)          */                               \
        SGB(0x2, 24);   /* recurrence(T+1)    */                               \
    }

    // even/odd persistent fragment buffers (static names, never swapped)
    bf16x8 fAh[4], fAl[4], fBh[4], fBl[4];

    // prologue: drain W1/b1 loads; stage tiles 0..5; pre-read frags(0)->FA
    asm volatile("s_waitcnt vmcnt(0)" ::: "memory");
#pragma unroll
    for (int j = 0; j < 6; ++j)
        STAGE(j, j)
    asm volatile("s_waitcnt vmcnt(10)" ::: "memory");   // tile 0 landed
    __builtin_amdgcn_s_barrier();
    asm volatile("" ::: "memory");
    RD8(0, fAh, fAl)

    // 4 phases (8 t) per iteration -> all ring offsets compile-time constant
    for (int w = 0; w < TSTEPS / 8; ++w) {
        const int tb = w * 8;
        PHASE(tb + 0)
        PHASE(tb + 2)
        PHASE(tb + 4)
        PHASE(tb + 6)
    }
#undef PHASE
#undef SGB
#undef MFMA_REC
#undef RD8
#undef STAGE

    // store spike counts; C-layout row = lg*4+r, col = l15
    float* cp = cnt_ws + (size_t)b0 * HIDDEN + hbase + l15;
#pragma unroll
    for (int r = 0; r < 4; ++r)
        cp[(size_t)(lg * 4 + r) * HIDDEN] = cnt[r];
}

// ---------- Fallback (proven R2 path) if ws too small ----------
__global__ __launch_bounds__(256, 1) void snn_mfma_lds(
    const float* __restrict__ x, const float* __restrict__ W1,
    const float* __restrict__ b1, float* __restrict__ cnt_ws)
{
    __shared__ short ldsA[2][2][16 * IN_DIM];
    const int bid  = blockIdx.x;
    const int hblk = bid >> 5;
    const int bblk = bid & 31;
    const int b0   = bblk * 16;
    const int tid  = threadIdx.x;
    const int wave = tid >> 6;
    const int lane = tid & 63;
    const int l15  = lane & 15;
    const int lg   = lane >> 4;
    const int hbase = hblk * 64 + wave * 16;

    bf16x8 whi[4], wlo[4];
    {
        const float* wp = W1 + (size_t)(hbase + l15) * IN_DIM + lg * 8;
#pragma unroll
        for (int kf = 0; kf < 4; ++kf) {
            const float4* p = reinterpret_cast<const float4*>(wp + kf * 32);
            cvt8s(p[0], p[1], 1.0f, &whi[kf], &wlo[kf]);
        }
    }
    const float b1h = b1[hbase + l15];
    const int m_w  = wave * 4 + lg;
    const int widx = m_w * IN_DIM + ((l15 ^ (m_w & 7)) * 8);
    const float* xrow = x + ((size_t)(b0 + m_w) * TSTEPS) * IN_DIM + l15 * 8;
    int ridx[4];
#pragma unroll
    for (int kf = 0; kf < 4; ++kf)
        ridx[kf] = l15 * IN_DIM + (((lg + 4 * kf) ^ (l15 & 7)) * 8);

    f32x4 mem = {0.f, 0.f, 0.f, 0.f};
    f32x4 cnt = {0.f, 0.f, 0.f, 0.f};
    {
        const float4* p = reinterpret_cast<const float4*>(xrow);
        bf16x8 h8, l8;
        cvt8s(p[0], p[1], 2.0f, &h8, &l8);
        *(bf16x8*)&ldsA[0][0][widx] = h8;
        *(bf16x8*)&ldsA[0][1][widx] = l8;
    }
    float4 rA0, rA1, rB0, rB1;
    {
        const float4* p1 = reinterpret_cast<const float4*>(xrow + 1 * IN_DIM);
        rA0 = p1[0]; rA1 = p1[1];
        const float4* p2 = reinterpret_cast<const float4*>(xrow + 2 * IN_DIM);
        rB0 = p2[0]; rB1 = p2[1];
    }
    __syncthreads();

#define SNN_BODY(T_CUR, RC0, RC1)                                              \
    {                                                                          \
        const int buf = (T_CUR) & 1;                                           \
        if ((T_CUR) + 1 < TSTEPS) {                                            \
            bf16x8 h8, l8;                                                     \
            cvt8s(RC0, RC1, 2.0f, &h8, &l8);                                   \
            *(bf16x8*)&ldsA[buf ^ 1][0][widx] = h8;                            \
            *(bf16x8*)&ldsA[buf ^ 1][1][widx] = l8;                            \
        }                                                                      \
        bf16x8 ahi[4], alo[4];                                                 \
        _Pragma("unroll")                                                      \
        for (int kf = 0; kf < 4; ++kf) {                                       \
            ahi[kf] = *(const bf16x8*)&ldsA[buf][0][ridx[kf]];                 \
            alo[kf] = *(const bf16x8*)&ldsA[buf][1][ridx[kf]];                 \
        }                                                                      \
        {                                                                      \
            int tld = (T_CUR) + 3;                                             \
            if (tld > TSTEPS - 1) tld = TSTEPS - 1;                            \
            const float4* p = reinterpret_cast<const float4*>(                 \
                xrow + (size_t)tld * IN_DIM);                                  \
            RC0 = p[0]; RC1 = p[1];                                            \
        }                                                                      \
        f32x4 chh = {b1h, b1h, b1h, b1h};                                      \
        f32x4 chl = {0.f, 0.f, 0.f, 0.f};                                      \
        f32x4 clh = {0.f, 0.f, 0.f, 0.f};                                      \
        _Pragma("unroll")                                                      \
        for (int kf = 0; kf < 4; ++kf) {                                       \
            chh = __builtin_amdgcn_mfma_f32_16x16x32_bf16(ahi[kf], whi[kf], chh, 0, 0, 0); \
            chl = __builtin_amdgcn_mfma_f32_16x16x32_bf16(ahi[kf], wlo[kf], chl, 0, 0, 0); \
            clh = __builtin_amdgcn_mfma_f32_16x16x32_bf16(alo[kf], whi[kf], clh, 0, 0, 0); \
        }                                                                      \
        _Pragma("unroll")                                                      \
        for (int r = 0; r < 4; ++r) {                                          \
            float cur = (chh[r] + chl[r]) + clh[r];                            \
            float dec = fmaf(BETA, mem[r], cur);                               \
            mem[r] = (mem[r] > THRESH) ? (dec - THRESH) : dec;                 \
            cnt[r] += (mem[r] > THRESH) ? 1.0f : 0.0f;                         \
        }                                                                      \
        __syncthreads();                                                       \
    }

    for (int t = 0; t < TSTEPS; t += 2) {
        SNN_BODY(t,     rA0, rA1)
        SNN_BODY(t + 1, rB0, rB1)
    }
#undef SNN_BODY

    float* cp = cnt_ws + (size_t)b0 * HIDDEN + hbase + l15;
#pragma unroll
    for (int r = 0; r < 4; ++r)
        cp[(size_t)(lg * 4 + r) * HIDDEN] = cnt[r];
}

// out[b,c] = (sum_h cnt[b,h] * W2[c,h]) / T + b2[c]
__global__ __launch_bounds__(64, 1) void snn_out(
    const float* __restrict__ cnt_ws, const float* __restrict__ W2,
    const float* __restrict__ b2, float* __restrict__ out)
{
    const int b = blockIdx.x;
    const int lane = threadIdx.x;
    float c8[8];
#pragma unroll
    for (int j = 0; j < 8; ++j)
        c8[j] = cnt_ws[(size_t)b * HIDDEN + lane + 64 * j];
#pragma unroll
    for (int c = 0; c < NCLASS; ++c) {
        float s = 0.f;
#pragma unroll
        for (int j = 0; j < 8; ++j)
            s = fmaf(c8[j], W2[c * HIDDEN + lane + 64 * j], s);
#pragma unroll
        for (int off = 32; off >= 1; off >>= 1)
            s += __shfl_xor(s, off, 64);
        if (lane == c)
            out[(size_t)b * NCLASS + c] = s * (1.0f / (float)TSTEPS) + b2[c];
    }
}

extern "C" void kernel_launch(void* const* d_in, const int* in_sizes, int n_in,
                              void* d_out, int out_size, void* d_ws, size_t ws_size,
                              hipStream_t stream) {
    const float* x  = (const float*)d_in[0];
    const float* W1 = (const float*)d_in[1];
    const float* b1 = (const float*)d_in[2];
    const float* W2 = (const float*)d_in[3];
    const float* b2 = (const float*)d_in[4];
    float* out = (float*)d_out;

    const size_t NX = (size_t)BATCH * TSTEPS * IN_DIM;      // 33.55M elems
    float* cnt_ws = (float*)d_ws;                           // [B, H], 1 MB
    unsigned short* xt = (unsigned short*)((char*)d_ws + (1u << 20));
    const size_t need = (1u << 20) + 2 * NX * sizeof(unsigned short);

    if (ws_size >= need) {
        conv_x2<<<dim3(32 * TSTEPS), dim3(256), 0, stream>>>(x, xt);
        snn_mfma_l<<<dim3(256), dim3(256), 0, stream>>>(xt, W1, b1, cnt_ws);
    } else {
        snn_mfma_lds<<<dim3(256), dim3(256), 0, stream>>>(x, W1, b1, cnt_ws);
    }
    snn_out<<<dim3(BATCH), dim3(64), 0, stream>>>(cnt_ws, W2, b2, out);
}